// Round 10
// baseline (575.583 us; speedup 1.0000x reference)
//
#include <hip/hip_runtime.h>

namespace {
constexpr int kL    = 2048;
constexpr int kV    = 25;
constexpr int kTL   = 8;
constexpr int kXsC  = kL * kV;          // 51200
constexpr long kXsN = 64L * kXsC;

typedef __attribute__((ext_vector_type(8)))  short bf16x8;
typedef __attribute__((ext_vector_type(16))) float f32x16;

__device__ __forceinline__ float b2f(unsigned short u) {
  union { unsigned u32; float f; } x; x.u32 = ((unsigned)u) << 16; return x.f;
}
__device__ __forceinline__ unsigned short f2b(float f) {
  union { float f; unsigned u; } x; x.f = f;
  unsigned r = x.u + 0x7FFF + ((x.u >> 16) & 1);
  return (unsigned short)(r >> 16);
}
__device__ __forceinline__ unsigned cvt_pk(float lo, float hi) {
  unsigned r;
  asm("v_cvt_pk_bf16_f32 %0, %1, %2" : "=v"(r) : "v"(lo), "v"(hi));
  return r;
}
}

// ws layout (ushort):
//  [0, 12288)      S2 A-frags bf16[2 mt2][12 kg][64 lane][8]  (W[c][k=p*64+ci], 32x32x16 A-layout)
//  [12288, 15360)  S1 B-frags bf16[3 p][2 ks][64 lane][8]     (A[p][v][w] 0-pad, 32x32x16 B-layout)
//  byte 30720      bias2 fp32[64][25]
__global__ void stgcn_pre(const float* __restrict__ A,
                          const float* __restrict__ cw,
                          const float* __restrict__ cb,
                          unsigned short* __restrict__ wsu) {
  int tid = blockIdx.x * 256 + threadIdx.x;
  int nthr = gridDim.x * 256;
  for (int i = tid; i < 2 * 12 * 64 * 8; i += nthr) {
    int j = i & 7, lane = (i >> 3) & 63;
    int rem = i >> 9;                 // 0..23
    int kg = rem % 12, mt2 = rem / 12;
    int c  = 32 * mt2 + (lane & 31);
    int p  = kg >> 2, ksl = kg & 3;
    int ci = 16 * ksl + 8 * (lane >> 5) + j;
    wsu[i] = f2b(cw[(p * 64 + c) * 64 + ci]);
  }
  for (int i = tid; i < 3 * 2 * 64 * 8; i += nthr) {
    int j = i & 7, lane = (i >> 3) & 63, ks = (i >> 9) & 1, p = i >> 10;
    int w = lane & 31;
    int v = 16 * ks + 8 * (lane >> 5) + j;
    float val = (v < kV && w < kV) ? A[(p * kV + v) * kV + w] : 0.f;
    wsu[12288 + i] = f2b(val);
  }
  float* bias2 = (float*)((char*)wsu + 30720);
  for (int i = tid; i < 64 * kV; i += nthr) {
    int c = i / kV, w = i % kV;
    float s = 0.f;
    for (int p = 0; p < 3; ++p) {
      float as = 0.f;
      for (int v = 0; v < kV; ++v) as += A[(p * kV + v) * kV + w];
      s += cb[p * 64 + c] * as;
    }
    bias2[i] = s;
  }
}

__global__ __launch_bounds__(512, 8)
void stgcn_main(const float* __restrict__ x,
                const unsigned short* __restrict__ wsu,
                float* __restrict__ out) {
  // Unioned LDS, 40960 B exactly -> 4 blocks/CU (4*512 = 2048 threads = CU max):
  //  Phase A/B : SX bf16 [m=ci*8+dl][40]  (8-us col blocks XOR'd by ci&3)
  //  p-loop    : sYs bf16 [nidx 224][64]  (octet o at o^(nidx&7)) -- union [0,14336)
  //  post-loop : sResB bf16 [c][nidx 200] = bf16(x_res + cnt*bias2) -- union [0,12800)
  __shared__ unsigned short sBuf[20480];

  const int t    = threadIdx.x;
  const int lane = t & 63;
  const int wid  = t >> 6;            // 0..7
  const int hi   = lane >> 5;         // 0..1
  const int l31  = lane & 31;

  // XCD-aware bijective swizzle (nwg=4096 % 8 == 0): contiguous l-tiles per XCD.
  const int b   = blockIdx.x + (int)gridDim.x * blockIdx.y;   // 0..4095
  const int w_  = (b & 7) * 512 + (b >> 3);
  const int lt  = w_ & 255;
  const int nb  = w_ >> 8;
  const int l0  = lt * kTL;

  const float* xn = x + (long)nb * kXsN;
  float* outn     = out + (long)nb * kXsN;
  const float* bias2 = (const float*)((const char*)wsu + 30720);

  // ---- Phase A: rolling window sums -> SX in LDS ----
  {
    const int ci = t >> 3, q = t & 7;
    const int rowb = ci * 8 * 40;
    if (q == 7) {
      const int c4 = ((3 ^ (ci & 3)) << 3) | 4;   // logical cols 28..31
      uint2 z = {0u, 0u};
      #pragma unroll
      for (int dl = 0; dl < 8; ++dl) *(uint2*)&sBuf[rowb + dl * 40 + c4] = z;
    } else {
      const int colL = 4 * q;
      const int c4 = (((colL >> 3) ^ (ci & 3)) << 3) | (colL & 7);
      const float* xr = xn + (long)ci * kXsC + (long)(l0 - 8) * kV + colL;
      const bool full = (q < 6);                  // q==6 -> only v=24 valid
      float a0 = 0.f, a1 = 0.f, a2 = 0.f, a3 = 0.f;
      if (l0) {
        #pragma unroll
        for (int j = 0; j < 9; ++j) {
          const float* r = xr + j * kV;
          a0 += r[0];
          if (full) { a1 += r[1]; a2 += r[2]; a3 += r[3]; }
        }
      } else {
        const float* r = xr + 8 * kV;
        a0 = r[0];
        if (full) { a1 = r[1]; a2 = r[2]; a3 = r[3]; }
      }
      #pragma unroll
      for (int dl = 0; dl < 8; ++dl) {
        uint2 o = { cvt_pk(a0, a1), cvt_pk(a2, a3) };
        *(uint2*)&sBuf[rowb + dl * 40 + c4] = o;
        if (dl < 7) {
          const float* pn = xr + (dl + 9) * kV;
          a0 += pn[0];
          if (full) { a1 += pn[1]; a2 += pn[2]; a3 += pn[3]; }
          if (l0) {
            const float* po = xr + dl * kV;
            a0 -= po[0];
            if (full) { a1 -= po[1]; a2 -= po[2]; a3 -= po[3]; }
          }
        }
      }
    }
  }
  __syncthreads();   // bar1

  // ---- Phase B: hoist A-fragments (p-invariant) ----
  bf16x8 af[2][2];
  #pragma unroll
  for (int mtl = 0; mtl < 2; ++mtl) {
    const int m  = 32 * (2 * wid + mtl) + l31;
    const int cia = m >> 3;
    #pragma unroll
    for (int ks = 0; ks < 2; ++ks) {
      const int vblk = 2 * ks + hi;
      af[mtl][ks] = *(const bf16x8*)&sBuf[m * 40 + ((vblk ^ (cia & 3)) << 3)];
    }
  }
  __syncthreads();   // bar2 -- SX dead, sBuf[0,14336) becomes sYs[224][64]

  // sYs rows 200..223 hold stale SX garbage -- safe: as S2's B-operand, row
  // nidx only feeds D column nidx (>=200 discarded at store). No zero-init.

  const int mt2 = wid & 1;
  const int ng  = wid >> 1;
  const int nnt = (ng < 3) ? 2 : 1;
  const int nt0 = (ng < 3) ? 2 * ng : 6;

  f32x16 acc[2];
  #pragma unroll
  for (int q = 0; q < 2; ++q)
    #pragma unroll
    for (int r = 0; r < 16; ++r) acc[q][r] = 0.f;

  const bool wok = (l31 < kV);

  // ---- S1: Y_p[(ci,dl)][w] -> sYs ----
  #define S1(p) {                                                             \
    _Pragma("unroll")                                                         \
    for (int mtl = 0; mtl < 2; ++mtl) {                                       \
      f32x16 cz;                                                              \
      _Pragma("unroll")                                                       \
      for (int r = 0; r < 16; ++r) cz[r] = 0.f;                               \
      _Pragma("unroll")                                                       \
      for (int ks = 0; ks < 2; ++ks) {                                        \
        bf16x8 bfr = *(const bf16x8*)&wsu[12288 + (((p) * 2 + ks) * 64 + lane) * 8]; \
        cz = __builtin_amdgcn_mfma_f32_32x32x16_bf16(af[mtl][ks], bfr, cz, 0, 0, 0); \
      }                                                                       \
      if (wok) {                                                              \
        _Pragma("unroll")                                                     \
        for (int r = 0; r < 16; ++r) {                                        \
          const int mo = (r & 3) + 8 * (r >> 2) + 4 * hi;                     \
          const int m  = 32 * (2 * wid + mtl) + mo;                           \
          const int ci = m >> 3;                                              \
          const int nidx = (m & 7) * kV + l31;                                \
          sBuf[nidx * 64 + (((ci >> 3) ^ (nidx & 7)) << 3) + (ci & 7)] =      \
              (unsigned short)cvt_pk(cz[r], cz[r]);                           \
        }                                                                     \
      }                                                                       \
    }                                                                         \
  }

  // ---- S2: acc += W_p^T Y_p ----
  #define S2(p) {                                                             \
    _Pragma("unroll")                                                         \
    for (int ksl = 0; ksl < 4; ++ksl) {                                       \
      bf16x8 wf = *(const bf16x8*)&wsu[((mt2 * 12 + (p) * 4 + ksl) * 64 + lane) * 8]; \
      _Pragma("unroll")                                                       \
      for (int q = 0; q < 2; ++q) {                                           \
        if (q < nnt) {                                                        \
          const int nidx = 32 * (nt0 + q) + l31;                              \
          const int o = 2 * ksl + hi;                                         \
          bf16x8 yf = *(const bf16x8*)&sBuf[nidx * 64 + ((o ^ (nidx & 7)) << 3)]; \
          acc[q] = __builtin_amdgcn_mfma_f32_32x32x16_bf16(wf, yf, acc[q], 0, 0, 0); \
        }                                                                     \
      }                                                                       \
    }                                                                         \
  }

  S1(0); __syncthreads();
  S2(0); __syncthreads();
  S1(1); __syncthreads();
  S2(1); __syncthreads();
  S1(2); __syncthreads();
  S2(2);

  #undef S1
  #undef S2

  __syncthreads();   // bar8 -- sYs dead, sBuf[0,12800) becomes sResB[64][200]

  // ---- Residual+bias reload: coalesced re-read of this block's x slice
  //      (L2/L3-hot from Phase A), folded with cnt*bias2, bf16 to LDS ----
  {
    const long xb = (long)l0 * kV;
    #pragma unroll
    for (int k = 0; k < 25; ++k) {
      const int i = t + 512 * k;          // 0..12799
      const int c = i / 200, rem = i - 200 * c;   // rem = l*25+wv = nidx
      const int l = rem / 25, wv = rem - 25 * l;
      const float xv = xn[(long)c * kXsC + xb + rem];
      const float cnt = lt ? 9.f : (float)(l + 1);
      sBuf[i] = f2b(fmaf(cnt, bias2[c * kV + wv], xv));
    }
  }
  __syncthreads();   // bar9

  // ---- Epilogue: + (residual + cnt*bias2) from LDS, ReLU, store ----
  #pragma unroll
  for (int q = 0; q < 2; ++q) {
    if (q < nnt) {
      const int nidx = 32 * (nt0 + q) + l31;
      if (nidx < 200) {
        const int dl = nidx / 25, wv = nidx - 25 * dl;
        const long base = (long)(l0 + dl) * kV + wv;
        #pragma unroll
        for (int r = 0; r < 16; ++r) {
          const int c = 32 * mt2 + (r & 3) + 8 * (r >> 2) + 4 * hi;
          float val = acc[q][r] + b2f(sBuf[c * 200 + nidx]);
          outn[(long)c * kXsC + base] = fmaxf(val, 0.f);
        }
      }
    }
  }
}

extern "C" void kernel_launch(void* const* d_in, const int* in_sizes, int n_in,
                              void* d_out, int out_size, void* d_ws, size_t ws_size,
                              hipStream_t stream) {
  const float* x  = (const float*)d_in[0];
  const float* A  = (const float*)d_in[1];
  const float* cw = (const float*)d_in[2];
  const float* cb = (const float*)d_in[3];
  unsigned short* wsu = (unsigned short*)d_ws;   // needs 37120 B

  hipLaunchKernelGGL(stgcn_pre, dim3(8), dim3(256), 0, stream, A, cw, cb, wsu);
  hipLaunchKernelGGL(stgcn_main, dim3(kL / kTL, 16), dim3(512), 0, stream,
                     x, wsu, (float*)d_out);
}

// Round 11
// 221.490 us; speedup vs baseline: 2.5987x; 2.5987x over previous
//
#include <hip/hip_runtime.h>

namespace {
constexpr int kL    = 2048;
constexpr int kV    = 25;
constexpr int kTL   = 8;
constexpr int kXsC  = kL * kV;          // 51200
constexpr long kXsN = 64L * kXsC;

typedef __attribute__((ext_vector_type(8)))  short bf16x8;
typedef __attribute__((ext_vector_type(16))) float f32x16;

__device__ __forceinline__ float b2f(unsigned short u) {
  union { unsigned u32; float f; } x; x.u32 = ((unsigned)u) << 16; return x.f;
}
__device__ __forceinline__ unsigned short f2b(float f) {
  union { float f; unsigned u; } x; x.f = f;
  unsigned r = x.u + 0x7FFF + ((x.u >> 16) & 1);
  return (unsigned short)(r >> 16);
}
__device__ __forceinline__ unsigned cvt_pk(float lo, float hi) {
  unsigned r;
  asm("v_cvt_pk_bf16_f32 %0, %1, %2" : "=v"(r) : "v"(lo), "v"(hi));
  return r;
}
}

// ws layout (ushort):
//  [0, 12288)      S2 A-frags bf16[2 mt2][12 kg][64 lane][8]  (W[c][k=p*64+ci], 32x32x16 A-layout)
//  [12288, 15360)  S1 B-frags bf16[3 p][2 ks][64 lane][8]     (A[p][v][w] 0-pad, 32x32x16 B-layout)
//  byte 30720      bias2 fp32[64][25]
__global__ void stgcn_pre(const float* __restrict__ A,
                          const float* __restrict__ cw,
                          const float* __restrict__ cb,
                          unsigned short* __restrict__ wsu) {
  int tid = blockIdx.x * 256 + threadIdx.x;
  int nthr = gridDim.x * 256;
  for (int i = tid; i < 2 * 12 * 64 * 8; i += nthr) {
    int j = i & 7, lane = (i >> 3) & 63;
    int rem = i >> 9;                 // 0..23
    int kg = rem % 12, mt2 = rem / 12;
    int c  = 32 * mt2 + (lane & 31);
    int p  = kg >> 2, ksl = kg & 3;
    int ci = 16 * ksl + 8 * (lane >> 5) + j;
    wsu[i] = f2b(cw[(p * 64 + c) * 64 + ci]);
  }
  for (int i = tid; i < 3 * 2 * 64 * 8; i += nthr) {
    int j = i & 7, lane = (i >> 3) & 63, ks = (i >> 9) & 1, p = i >> 10;
    int w = lane & 31;
    int v = 16 * ks + 8 * (lane >> 5) + j;
    float val = (v < kV && w < kV) ? A[(p * kV + v) * kV + w] : 0.f;
    wsu[12288 + i] = f2b(val);
  }
  float* bias2 = (float*)((char*)wsu + 30720);
  for (int i = tid; i < 64 * kV; i += nthr) {
    int c = i / kV, w = i % kV;
    float s = 0.f;
    for (int p = 0; p < 3; ++p) {
      float as = 0.f;
      for (int v = 0; v < kV; ++v) as += A[(p * kV + v) * kV + w];
      s += cb[p * 64 + c] * as;
    }
    bias2[i] = s;
  }
}

__global__ __launch_bounds__(512, 4)   // R10's (512,8) forced VGPR=32 -> spills; (512,4)
void stgcn_main(const float* __restrict__ x,          // gives ~52 VGPR <= 64, so the HW can
                const unsigned short* __restrict__ wsu, // still co-schedule 4 blocks/CU (LDS-limited)
                float* __restrict__ out) {
  // Unioned LDS, 40960 B exactly -> 4 blocks/CU (4*512 = 2048 threads = CU max):
  //  Phase A/B : SX bf16 [m=ci*8+dl][40]  (8-us col blocks XOR'd by ci&3)
  //  p-loop    : sYs bf16 [nidx 224][64]  (octet o at o^(nidx&7)) -- union [0,14336)
  //  post-loop : sResB bf16 [c][nidx 200] = bf16(x_res + cnt*bias2) -- union [0,12800)
  __shared__ unsigned short sBuf[20480];

  const int t    = threadIdx.x;
  const int lane = t & 63;
  const int wid  = t >> 6;            // 0..7
  const int hi   = lane >> 5;         // 0..1
  const int l31  = lane & 31;

  // XCD-aware bijective swizzle (nwg=4096 % 8 == 0): contiguous l-tiles per XCD.
  const int b   = blockIdx.x + (int)gridDim.x * blockIdx.y;   // 0..4095
  const int w_  = (b & 7) * 512 + (b >> 3);
  const int lt  = w_ & 255;
  const int nb  = w_ >> 8;
  const int l0  = lt * kTL;

  const float* xn = x + (long)nb * kXsN;
  float* outn     = out + (long)nb * kXsN;
  const float* bias2 = (const float*)((const char*)wsu + 30720);

  // ---- Phase A: rolling window sums -> SX in LDS ----
  {
    const int ci = t >> 3, q = t & 7;
    const int rowb = ci * 8 * 40;
    if (q == 7) {
      const int c4 = ((3 ^ (ci & 3)) << 3) | 4;   // logical cols 28..31
      uint2 z = {0u, 0u};
      #pragma unroll
      for (int dl = 0; dl < 8; ++dl) *(uint2*)&sBuf[rowb + dl * 40 + c4] = z;
    } else {
      const int colL = 4 * q;
      const int c4 = (((colL >> 3) ^ (ci & 3)) << 3) | (colL & 7);
      const float* xr = xn + (long)ci * kXsC + (long)(l0 - 8) * kV + colL;
      const bool full = (q < 6);                  // q==6 -> only v=24 valid
      float a0 = 0.f, a1 = 0.f, a2 = 0.f, a3 = 0.f;
      if (l0) {
        #pragma unroll
        for (int j = 0; j < 9; ++j) {
          const float* r = xr + j * kV;
          a0 += r[0];
          if (full) { a1 += r[1]; a2 += r[2]; a3 += r[3]; }
        }
      } else {
        const float* r = xr + 8 * kV;
        a0 = r[0];
        if (full) { a1 = r[1]; a2 = r[2]; a3 = r[3]; }
      }
      #pragma unroll
      for (int dl = 0; dl < 8; ++dl) {
        uint2 o = { cvt_pk(a0, a1), cvt_pk(a2, a3) };
        *(uint2*)&sBuf[rowb + dl * 40 + c4] = o;
        if (dl < 7) {
          const float* pn = xr + (dl + 9) * kV;
          a0 += pn[0];
          if (full) { a1 += pn[1]; a2 += pn[2]; a3 += pn[3]; }
          if (l0) {
            const float* po = xr + dl * kV;
            a0 -= po[0];
            if (full) { a1 -= po[1]; a2 -= po[2]; a3 -= po[3]; }
          }
        }
      }
    }
  }
  __syncthreads();   // bar1

  // ---- Phase B: hoist A-fragments (p-invariant) ----
  bf16x8 af[2][2];
  #pragma unroll
  for (int mtl = 0; mtl < 2; ++mtl) {
    const int m  = 32 * (2 * wid + mtl) + l31;
    const int cia = m >> 3;
    #pragma unroll
    for (int ks = 0; ks < 2; ++ks) {
      const int vblk = 2 * ks + hi;
      af[mtl][ks] = *(const bf16x8*)&sBuf[m * 40 + ((vblk ^ (cia & 3)) << 3)];
    }
  }
  __syncthreads();   // bar2 -- SX dead, sBuf[0,14336) becomes sYs[224][64]

  // sYs rows 200..223 hold stale SX garbage -- safe: as S2's B-operand, row
  // nidx only feeds D column nidx (>=200 discarded at store). No zero-init.

  const int mt2 = wid & 1;
  const int ng  = wid >> 1;
  const int nnt = (ng < 3) ? 2 : 1;
  const int nt0 = (ng < 3) ? 2 * ng : 6;

  f32x16 acc[2];
  #pragma unroll
  for (int q = 0; q < 2; ++q)
    #pragma unroll
    for (int r = 0; r < 16; ++r) acc[q][r] = 0.f;

  const bool wok = (l31 < kV);

  // ---- S1: Y_p[(ci,dl)][w] -> sYs ----
  #define S1(p) {                                                             \
    _Pragma("unroll")                                                         \
    for (int mtl = 0; mtl < 2; ++mtl) {                                       \
      f32x16 cz;                                                              \
      _Pragma("unroll")                                                       \
      for (int r = 0; r < 16; ++r) cz[r] = 0.f;                               \
      _Pragma("unroll")                                                       \
      for (int ks = 0; ks < 2; ++ks) {                                        \
        bf16x8 bfr = *(const bf16x8*)&wsu[12288 + (((p) * 2 + ks) * 64 + lane) * 8]; \
        cz = __builtin_amdgcn_mfma_f32_32x32x16_bf16(af[mtl][ks], bfr, cz, 0, 0, 0); \
      }                                                                       \
      if (wok) {                                                              \
        _Pragma("unroll")                                                     \
        for (int r = 0; r < 16; ++r) {                                        \
          const int mo = (r & 3) + 8 * (r >> 2) + 4 * hi;                     \
          const int m  = 32 * (2 * wid + mtl) + mo;                           \
          const int ci = m >> 3;                                              \
          const int nidx = (m & 7) * kV + l31;                                \
          sBuf[nidx * 64 + (((ci >> 3) ^ (nidx & 7)) << 3) + (ci & 7)] =      \
              (unsigned short)cvt_pk(cz[r], cz[r]);                           \
        }                                                                     \
      }                                                                       \
    }                                                                         \
  }

  // ---- S2: acc += W_p^T Y_p ----
  #define S2(p) {                                                             \
    _Pragma("unroll")                                                         \
    for (int ksl = 0; ksl < 4; ++ksl) {                                       \
      bf16x8 wf = *(const bf16x8*)&wsu[((mt2 * 12 + (p) * 4 + ksl) * 64 + lane) * 8]; \
      _Pragma("unroll")                                                       \
      for (int q = 0; q < 2; ++q) {                                           \
        if (q < nnt) {                                                        \
          const int nidx = 32 * (nt0 + q) + l31;                              \
          const int o = 2 * ksl + hi;                                         \
          bf16x8 yf = *(const bf16x8*)&sBuf[nidx * 64 + ((o ^ (nidx & 7)) << 3)]; \
          acc[q] = __builtin_amdgcn_mfma_f32_32x32x16_bf16(wf, yf, acc[q], 0, 0, 0); \
        }                                                                     \
      }                                                                       \
    }                                                                         \
  }

  S1(0); __syncthreads();
  S2(0); __syncthreads();
  S1(1); __syncthreads();
  S2(1); __syncthreads();
  S1(2); __syncthreads();
  S2(2);

  #undef S1
  #undef S2

  __syncthreads();   // bar8 -- sYs dead, sBuf[0,12800) becomes sResB[64][200]

  // ---- Residual+bias reload: coalesced re-read of this block's x slice
  //      (L2/L3-hot from Phase A), folded with cnt*bias2, bf16 to LDS ----
  {
    const long xb = (long)l0 * kV;
    #pragma unroll
    for (int k = 0; k < 25; ++k) {
      const int i = t + 512 * k;          // 0..12799
      const int c = i / 200, rem = i - 200 * c;   // rem = l*25+wv = nidx
      const int l = rem / 25, wv = rem - 25 * l;
      const float xv = xn[(long)c * kXsC + xb + rem];
      const float cnt = lt ? 9.f : (float)(l + 1);
      sBuf[i] = f2b(fmaf(cnt, bias2[c * kV + wv], xv));
    }
  }
  __syncthreads();   // bar9

  // ---- Epilogue: + (residual + cnt*bias2) from LDS, ReLU, store ----
  #pragma unroll
  for (int q = 0; q < 2; ++q) {
    if (q < nnt) {
      const int nidx = 32 * (nt0 + q) + l31;
      if (nidx < 200) {
        const int dl = nidx / 25, wv = nidx - 25 * dl;
        const long base = (long)(l0 + dl) * kV + wv;
        #pragma unroll
        for (int r = 0; r < 16; ++r) {
          const int c = 32 * mt2 + (r & 3) + 8 * (r >> 2) + 4 * hi;
          float val = acc[q][r] + b2f(sBuf[c * 200 + nidx]);
          outn[(long)c * kXsC + base] = fmaxf(val, 0.f);
        }
      }
    }
  }
}

extern "C" void kernel_launch(void* const* d_in, const int* in_sizes, int n_in,
                              void* d_out, int out_size, void* d_ws, size_t ws_size,
                              hipStream_t stream) {
  const float* x  = (const float*)d_in[0];
  const float* A  = (const float*)d_in[1];
  const float* cw = (const float*)d_in[2];
  const float* cb = (const float*)d_in[3];
  unsigned short* wsu = (unsigned short*)d_ws;   // needs 37120 B

  hipLaunchKernelGGL(stgcn_pre, dim3(8), dim3(256), 0, stream, A, cw, cb, wsu);
  hipLaunchKernelGGL(stgcn_main, dim3(kL / kTL, 16), dim3(512), 0, stream,
                     x, wsu, (float*)d_out);
}